// Round 12
// baseline (719.672 us; speedup 1.0000x reference)
//
#include <hip/hip_runtime.h>

typedef unsigned short ushort_t;
typedef __attribute__((ext_vector_type(8))) short bf16x8;
typedef __attribute__((ext_vector_type(4))) float f32x4;

#define NN 50000
#define NE 600000
#define DD 128
#define LL 3
#define GG 512

__device__ __forceinline__ float b2f(ushort_t u){ return __uint_as_float(((unsigned)u)<<16); }
__device__ __forceinline__ ushort_t f2b(float f){
    unsigned x = __float_as_uint(f);
    return (ushort_t)((x + 0x7fffu + ((x>>16)&1u)) >> 16);
}

// ---- marker for host-side input-layout mismatch (f32 out) ----
__global__ void k_mark(float* __restrict__ out, float val, int n){
    int i = blockIdx.x*256 + threadIdx.x; if (i >= n) return;
    out[i] = (i == 0) ? val : 0.f;
}

// ---- fused setup: weight frag-convert + group offsets + zero cnt + zero SR ----
// ranges: [0,180224) wconv | [.., +513) goff | [.., +50000) cnt=0 | [.., +2048) SR=0
struct WPtrs { const float* p[11]; };
__global__ void k_setup(WPtrs wp, ushort_t* __restrict__ Wf,
                        const int* __restrict__ bids, int* __restrict__ goff,
                        int* __restrict__ cnt, float* __restrict__ SR){
    int idx = blockIdx.x*256 + threadIdx.x;
    if (idx < 180224){
        int m = idx >> 14, r = idx & 16383;
        int i = r & 7, l2 = (r >> 3) & 63, s = (r >> 9) & 3, n = r >> 11;
        int k   = s*32 + (l2 >> 4)*8 + i;
        int col = n*16 + (l2 & 15);
        Wf[idx] = f2b(wp.p[m][k*DD + col]);
    } else if (idx < 180737){
        int g = idx - 180224;            // 0..512
        int lo = 0, hi = NN;
        while (lo < hi){ int mid = (lo+hi) >> 1; if (bids[mid] < g) lo = mid+1; else hi = mid; }
        goff[g] = lo;
    } else if (idx < 230737){
        cnt[idx - 180737] = 0;
    } else if (idx < 232785){
        SR[idx - 230737] = 0.f;
    }
}

// ---- layer-0 message table: yrows[di][c] = relu(emb[di]@linW + linB), 6x128 ----
__global__ void k_lin0(const float* __restrict__ emb, const float* __restrict__ linW,
                       const float* __restrict__ linB, float* __restrict__ yrows){
    int di = blockIdx.x;          // 6
    int c  = threadIdx.x;         // 128
    float acc = linB[c];
    for (int k = 0; k < DD; k++) acc = fmaf(emb[di*DD + k], linW[k*DD + c], acc);
    yrows[di*DD + c] = fmaxf(acc, 0.f);
}

// ---------------- CSR: count (int4) ----------------
__global__ void k_count(const int* __restrict__ dst, int* __restrict__ cnt){
    int e4 = blockIdx.x*256 + threadIdx.x; if (e4 >= NE/4) return;
    int4 dv = ((const int4*)dst)[e4];
    atomicAdd(&cnt[dv.x], 1); atomicAdd(&cnt[dv.y], 1);
    atomicAdd(&cnt[dv.z], 1); atomicAdd(&cnt[dv.w], 1);
}

// ---------------- CSR: single-block scan (1024 threads, ~49 elems each) ----------------
__global__ __launch_bounds__(1024) void k_scan(const int* __restrict__ cnt,
                                               int* __restrict__ rowptr,
                                               int* __restrict__ cursor){
    __shared__ int ps[1024];
    int t = threadIdx.x;
    const int CH = (NN + 1023)/1024;   // 49
    int b0 = t*CH, b1 = b0 + CH; if (b1 > NN) b1 = NN; if (b0 > NN) b0 = NN;
    int s = 0;
    for (int i = b0; i < b1; i++) s += cnt[i];
    ps[t] = s; __syncthreads();
    for (int off = 1; off < 1024; off <<= 1){
        int v = (t >= off) ? ps[t - off] : 0;
        __syncthreads();
        ps[t] += v;
        __syncthreads();
    }
    int run = (t == 0) ? 0 : ps[t-1];
    for (int i = b0; i < b1; i++){
        rowptr[i] = run; cursor[i] = run; run += cnt[i];
    }
    if (t == 1023) rowptr[NN] = NE;
}

// ---------------- CSR: fill (int4 loads) ----------------
__global__ void k_fill(const int* __restrict__ src, const int* __restrict__ dst,
                       int* __restrict__ cursor, int* __restrict__ eidx){
    int e4 = blockIdx.x*256 + threadIdx.x; if (e4 >= NE/4) return;
    int4 dv = ((const int4*)dst)[e4];
    int4 sv = ((const int4*)src)[e4];
    int p0 = atomicAdd(&cursor[dv.x], 1); eidx[p0] = sv.x;
    int p1 = atomicAdd(&cursor[dv.y], 1); eidx[p1] = sv.y;
    int p2 = atomicAdd(&cursor[dv.z], 1); eidx[p2] = sv.z;
    int p3 = atomicAdd(&cursor[dv.w], 1); eidx[p3] = sv.w;
}

// ---------------- MFMA GEMM: C[M,128] = op(A') @ W  (bf16, fp32 accum) ----
// AM: 0 plain A | 2 A'=relu(bn(A)) | 3 A'=gather: relu(bn(A))*(1+eps)+sum yb[src]
//     4 A'=layer0 gather: emb[d[row]]*(1+eps)+sum yrows[d[src]]  (LUTs in LDS)
// OM: 0 plain | 1 relu(C+bias).  ST: column sum/sumsq of C -> stats_out.
template<int AM, int OM, int ST>
__global__ __launch_bounds__(256) void k_gemm(
    const ushort_t* __restrict__ A, const ushort_t* __restrict__ Wf,
    const float* __restrict__ bias,
    const float* __restrict__ bnstats, const float* __restrict__ bng,
    const float* __restrict__ bnb,
    const ushort_t* __restrict__ msg,
    const int* __restrict__ rowptr, const int* __restrict__ eidx,
    const int* __restrict__ darr, const float* __restrict__ emb6,
    const float* __restrict__ yrows, const float* __restrict__ epsP, int lidx,
    ushort_t* __restrict__ C, float* __restrict__ stats_out, int M)
{
    __shared__ float ssl[256];
    __shared__ float sred[256];
    __shared__ float lrep[64*132];
    __shared__ float luts[(AM==4) ? 2*6*132 : 1];   // yL[6][132], eL[6][132]

    const int t = threadIdx.x;
    const int w = t >> 6, l = t & 63;
    const int rowBlk = blockIdx.x*64, rowBase = rowBlk + w*16;
    const int lm = l & 15, kg = l >> 4;

    if ((AM == 2 || AM == 3) && t < 128){
        float mu  = bnstats[t] * (1.0f/NN);
        float var = bnstats[t + DD] * (1.0f/NN) - mu*mu;
        float sc  = rsqrtf(fmaxf(var, 0.f) + 1e-5f) * bng[t];
        ssl[t] = sc;
        ssl[t + DD] = bnb[t] - mu*sc;
    }
    if (AM == 4){
        for (int i = t; i < 6*DD; i += 256){
            int r6 = i >> 7, c = i & 127;
            luts[r6*132 + c]         = yrows[i];
            luts[6*132 + r6*132 + c] = emb6[i];
        }
    }
    if (ST) sred[t] = 0.f;
    __syncthreads();

    int arow = rowBase + lm;
    if (arow >= M) arow = M - 1;          // clamp; pad rows masked at store/stats

    bf16x8 af[4];
    if (AM == 0 || AM == 2){
        const ushort_t* ap = A + (size_t)arow*DD + kg*8;
#pragma unroll
        for (int s = 0; s < 4; s++){
            bf16x8 ar = *(const bf16x8*)(ap + s*32);
            if (AM == 0){
                af[s] = ar;
            } else {
                int k0 = s*32 + kg*8;
#pragma unroll
                for (int i = 0; i < 8; i++){
                    float v = b2f((ushort_t)ar[i]);
                    v = fmaxf(fmaf(v, ssl[k0+i], ssl[DD+k0+i]), 0.f);
                    ((ushort_t*)&af[s])[i] = f2b(v);
                }
            }
        }
    } else {
        float z[4][8];
        float epl = 1.0f + epsP[lidx];
        if (AM == 3){
            const ushort_t* ap = A + (size_t)arow*DD + kg*8;
#pragma unroll
            for (int s = 0; s < 4; s++){
                bf16x8 ar = *(const bf16x8*)(ap + s*32);
                int k0 = s*32 + kg*8;
#pragma unroll
                for (int i = 0; i < 8; i++)
                    z[s][i] = fmaxf(fmaf(b2f((ushort_t)ar[i]), ssl[k0+i], ssl[DD+k0+i]), 0.f) * epl;
            }
        } else {
            int dv = darr[arow]; dv = dv < 0 ? 0 : (dv > 5 ? 5 : dv);
            const float* ep = luts + 6*132 + dv*132 + kg*8;
#pragma unroll
            for (int s = 0; s < 4; s++)
#pragma unroll
                for (int i = 0; i < 8; i++)
                    z[s][i] = ep[s*32 + i] * epl;
        }
        int e0 = rowptr[arow], e1 = rowptr[arow+1];
        int e = e0;
        if (AM == 3){
            for (; e + 1 < e1; e += 2){
                int s0 = eidx[e], s1 = eidx[e+1];
                const ushort_t* m0 = msg + (size_t)s0*DD + kg*8;
                const ushort_t* m1 = msg + (size_t)s1*DD + kg*8;
#pragma unroll
                for (int s = 0; s < 4; s++){
                    bf16x8 v0 = *(const bf16x8*)(m0 + s*32);
                    bf16x8 v1 = *(const bf16x8*)(m1 + s*32);
#pragma unroll
                    for (int i = 0; i < 8; i++)
                        z[s][i] += b2f((ushort_t)v0[i]) + b2f((ushort_t)v1[i]);
                }
            }
            for (; e < e1; e++){
                int s0 = eidx[e];
                const ushort_t* m0 = msg + (size_t)s0*DD + kg*8;
#pragma unroll
                for (int s = 0; s < 4; s++){
                    bf16x8 v0 = *(const bf16x8*)(m0 + s*32);
#pragma unroll
                    for (int i = 0; i < 8; i++) z[s][i] += b2f((ushort_t)v0[i]);
                }
            }
        } else {
            for (; e < e1; e++){
                int di = darr[eidx[e]]; di = di < 0 ? 0 : (di > 5 ? 5 : di);
                const float* yp = luts + di*132 + kg*8;
#pragma unroll
                for (int s = 0; s < 4; s++)
#pragma unroll
                    for (int i = 0; i < 8; i++) z[s][i] += yp[s*32 + i];
            }
        }
#pragma unroll
        for (int s = 0; s < 4; s++)
#pragma unroll
            for (int i = 0; i < 8; i++) ((ushort_t*)&af[s])[i] = f2b(z[s][i]);
    }

    f32x4 acc[8];
#pragma unroll
    for (int n = 0; n < 8; n++) acc[n] = (f32x4){0.f,0.f,0.f,0.f};
#pragma unroll
    for (int s = 0; s < 4; s++){
#pragma unroll
        for (int n = 0; n < 8; n++){
            bf16x8 bfr = *(const bf16x8*)(Wf + (size_t)((n*4 + s)*64 + l)*8);
            acc[n] = __builtin_amdgcn_mfma_f32_16x16x32_bf16(af[s], bfr, acc[n], 0, 0, 0);
        }
    }

    // transform + stats + LDS repack (D: col=n*16+lm, local row = w*16+kg*4+j)
#pragma unroll
    for (int n = 0; n < 8; n++){
        int col = n*16 + lm;
        float cs = 0.f, cq = 0.f;
#pragma unroll
        for (int j = 0; j < 4; j++){
            float v = acc[n][j];
            if (OM == 1) v = fmaxf(v + bias[col], 0.f);
            lrep[(w*16 + kg*4 + j)*132 + col] = v;
            if (ST && (rowBase + kg*4 + j) < M){ cs += v; cq += v*v; }
        }
        if (ST){
            cs += __shfl_xor(cs, 16); cs += __shfl_xor(cs, 32);
            cq += __shfl_xor(cq, 16); cq += __shfl_xor(cq, 32);
            if (kg == 0){
                atomicAdd(&sred[col], cs);
                atomicAdd(&sred[col + DD], cq);
            }
        }
    }
    __syncthreads();

    // coalesced store: thread t -> local row t&63, 32-col segment (t>>6)
    {
        int lr = t & 63;
        int gr = rowBlk + lr;
        if (gr < M){
            int seg = (t >> 6) * 32;
            const float* lp = lrep + lr*132 + seg;
            bf16x8 o0, o1, o2, o3;
#pragma unroll
            for (int i = 0; i < 8; i++){
                o0[i] = (short)f2b(lp[i]);
                o1[i] = (short)f2b(lp[8+i]);
                o2[i] = (short)f2b(lp[16+i]);
                o3[i] = (short)f2b(lp[24+i]);
            }
            ushort_t* cp = C + (size_t)gr*DD + seg;
            *(bf16x8*)(cp)      = o0;
            *(bf16x8*)(cp + 8)  = o1;
            *(bf16x8*)(cp + 16) = o2;
            *(bf16x8*)(cp + 24) = o3;
        }
    }

    if (ST){
        __syncthreads();
        atomicAdd(&stats_out[t], sred[t]);
    }
}

// ---------------- pooling with inline BN+ReLU (bf16 in, f32 out) ----------------
__global__ void k_poolbn(const ushort_t* __restrict__ h,
                         const float* __restrict__ bnstats, const float* __restrict__ bng,
                         const float* __restrict__ bnb,
                         const int* __restrict__ goff, float* __restrict__ outp,
                         float* __restrict__ outf){
    int g = blockIdx.x;
    int c = threadIdx.x;           // 128 threads
    float mu  = bnstats[c] * (1.0f/NN);
    float var = bnstats[c + DD] * (1.0f/NN) - mu*mu;
    float sc  = rsqrtf(fmaxf(var, 0.f) + 1e-5f) * bng[c];
    float sh  = bnb[c] - mu*sc;
    int r0 = goff[g], r1 = goff[g+1];
    float acc = 0.f;
    for (int r = r0; r < r1; r++)
        acc += fmaxf(fmaf(b2f(h[(size_t)r*DD + c]), sc, sh), 0.f);
    float m = acc / fmaxf((float)(r1 - r0), 1.0f);
    outp[g*DD + c] = m;
    if (outf) outf[g*DD + c] = m;
}

// ---------------- predict head (fp32) ----------------
__global__ void k_pred1(const float* __restrict__ hg, const float* __restrict__ W1,
                        const float* __restrict__ b1, float* __restrict__ ph){
    int idx = blockIdx.x*256 + threadIdx.x;
    if (idx >= GG*256) return;
    int g = idx >> 8, j = idx & 255;
    float acc = b1[j];
    for (int k = 0; k < DD; k++) acc = fmaf(hg[g*DD + k], W1[k*256 + j], acc);
    ph[idx] = fmaxf(acc, 0.f);
}
__global__ void k_pred2(const float* __restrict__ ph, const float* __restrict__ W2,
                        const float* __restrict__ b2, float* __restrict__ out){
    int g = blockIdx.x*256 + threadIdx.x; if (g >= GG) return;
    float acc = b2[0];
    for (int k = 0; k < 256; k++) acc = fmaf(ph[g*256 + k], W2[k], acc);
    out[g] = acc;
}

extern "C" void kernel_launch(void* const* d_in, const int* in_sizes, int n_in,
                              void* d_out, int out_size, void* d_ws, size_t ws_size,
                              hipStream_t stream){
    float* out = (float*)d_out;
    const int OUT_N = GG + GG*DD + LL*GG*DD;      // 262656

    static const int EXP[24] = {50000,600000,600000,50000, 768,49152,384,49152,384,384,
                                49152,3,384,384,16384,128,128,16384,128,128,
                                32768,256,256,1};
    int bad = -1;
    if (n_in != 24) bad = 50;
    else for (int i = 0; i < 24; i++) if (in_sizes[i] != EXP[i]) { bad = i; break; }
    if (bad >= 0){
        k_mark<<<(OUT_N+255)/256, 256, 0, stream>>>(out, 2048.0f + (float)bad, OUT_N);
        return;
    }

    const int* d    = (const int*)d_in[0];
    const int* src  = (const int*)d_in[1];
    const int* dst  = (const int*)d_in[2];
    const int* bids = (const int*)d_in[3];
    const float* emb  = (const float*)d_in[4];
    const float* linW = (const float*)d_in[5];
    const float* linB = (const float*)d_in[6];
    const float* W1   = (const float*)d_in[7];
    const float* g1   = (const float*)d_in[8];
    const float* b1   = (const float*)d_in[9];
    const float* W2   = (const float*)d_in[10];
    const float* epsA = (const float*)d_in[11];
    const float* bng  = (const float*)d_in[12];
    const float* bnb  = (const float*)d_in[13];
    const float* pW1  = (const float*)d_in[14];
    const float* pg1  = (const float*)d_in[15];
    const float* pb1  = (const float*)d_in[16];
    const float* pW2  = (const float*)d_in[17];
    const float* pbng = (const float*)d_in[18];
    const float* pbnb = (const float*)d_in[19];
    const float* prW1 = (const float*)d_in[20];
    const float* prb1 = (const float*)d_in[21];
    const float* prW2 = (const float*)d_in[22];
    const float* prb2 = (const float*)d_in[23];

    // ---- workspace (~45 MB) ----
    ushort_t* xb  = (ushort_t*)d_ws;              // NN*DD bf16 (state)
    ushort_t* yb  = xb + (size_t)NN*DD;           // messages
    ushort_t* zb  = yb + (size_t)NN*DD;           // t = z@W1
    ushort_t* Wf  = zb + (size_t)NN*DD;           // 11*16384 bf16
    float* SR    = (float*)(Wf + 11*16384);       // 8*256 stats regions
    float* yrows = SR + 8*256;                    // 6*128 layer-0 message LUT
    float* hg    = yrows + 6*DD;                  // GG*DD
    float* ph    = hg + (size_t)GG*DD;            // GG*256
    int* cnt    = (int*)(ph + (size_t)GG*256);
    int* rowptr = cnt + NN;                       // N+1
    int* cursor = rowptr + NN + 1;
    int* eidx   = cursor + NN;                    // E
    int* goff   = eidx + NE;                      // G+1

    float* out_pred   = out;
    float* out_hgraph = out + GG;
    float* out_hmeans = out + GG + GG*DD;

    const int GEMM_GRID = (NN + 63)/64;           // 782
    const int E4_GRID   = (NE/4 + 255)/256;       // 586
    const int SETUP_GRID= (232785 + 255)/256;     // 910

    WPtrs wp;
    for (int i = 0; i < 3; i++){
        wp.p[i]   = linW + (size_t)i*DD*DD;
        wp.p[3+i] = W1   + (size_t)i*DD*DD;
        wp.p[6+i] = W2   + (size_t)i*DD*DD;
    }
    wp.p[9] = pW1; wp.p[10] = pW2;
    const ushort_t* WfLin = Wf;
    const ushort_t* WfW1  = Wf + 3*16384;
    const ushort_t* WfW2  = Wf + 6*16384;
    const ushort_t* WfPW1 = Wf + 9*16384;
    const ushort_t* WfPW2 = Wf + 10*16384;

    // setup (wconv + goff + zero cnt/SR) + layer-0 LUT + CSR
    k_setup<<<SETUP_GRID, 256, 0, stream>>>(wp, Wf, bids, goff, cnt, SR);
    k_lin0<<<6, 128, 0, stream>>>(emb, linW, linB, yrows);
    k_count<<<E4_GRID, 256, 0, stream>>>(dst, cnt);
    k_scan<<<1, 1024, 0, stream>>>(cnt, rowptr, cursor);
    k_fill<<<E4_GRID, 256, 0, stream>>>(src, dst, cursor, eidx);

    // ---- layer 0: gather-from-LUT GEMM -> W2 GEMM -> pool ----
    k_gemm<4,0,1><<<GEMM_GRID, 256, 0, stream>>>(nullptr, WfW1, nullptr,
        nullptr, nullptr, nullptr, nullptr, rowptr, eidx, d, emb, yrows, epsA, 0,
        zb, SR + 0*256, NN);
    k_gemm<2,0,1><<<GEMM_GRID, 256, 0, stream>>>(zb, WfW2, nullptr,
        SR + 0*256, g1, b1, nullptr, nullptr, nullptr, nullptr, nullptr, nullptr, nullptr, 0,
        xb, SR + 1*256, NN);
    k_poolbn<<<GG, 128, 0, stream>>>(xb, SR + 1*256, bng, bnb, goff, out_hmeans, nullptr);

    // ---- layers 1,2 ----
    for (int l = 1; l < LL; l++){
        const float* pstat = SR + (2*l - 1)*256;
        const float* pg    = bng + (size_t)(l-1)*DD;
        const float* pb    = bnb + (size_t)(l-1)*DD;
        float* statsIn  = SR + (2*l)*256;
        float* statsOut = SR + (2*l + 1)*256;

        // yb = relu(relu(bn(xb)) @ lin_W + bias)
        k_gemm<2,1,0><<<GEMM_GRID, 256, 0, stream>>>(xb, WfLin + (size_t)l*16384,
            linB + (size_t)l*DD, pstat, pg, pb,
            nullptr, nullptr, nullptr, nullptr, nullptr, nullptr, nullptr, 0,
            yb, nullptr, NN);
        // zb = [relu(bn(xb))*(1+eps) + gather(yb)] @ mlp_W1  (+stats)
        k_gemm<3,0,1><<<GEMM_GRID, 256, 0, stream>>>(xb, WfW1 + (size_t)l*16384,
            nullptr, pstat, pg, pb,
            yb, rowptr, eidx, nullptr, nullptr, nullptr, epsA, l,
            zb, statsIn, NN);
        // xb = relu(bn(zb)) @ mlp_W2  (+stats)
        k_gemm<2,0,1><<<GEMM_GRID, 256, 0, stream>>>(zb, WfW2 + (size_t)l*16384,
            nullptr, statsIn, g1 + (size_t)l*DD, b1 + (size_t)l*DD,
            nullptr, nullptr, nullptr, nullptr, nullptr, nullptr, nullptr, 0,
            xb, statsOut, NN);
        k_poolbn<<<GG, 128, 0, stream>>>(xb, statsOut, bng + (size_t)l*DD, bnb + (size_t)l*DD,
                                         goff, out_hmeans + (size_t)l*GG*DD, nullptr);
    }

    // ---- pooling MLP ----
    k_gemm<2,0,1><<<GEMM_GRID, 256, 0, stream>>>(xb, WfPW1, nullptr,
        SR + 5*256, bng + 2*DD, bnb + 2*DD,
        nullptr, nullptr, nullptr, nullptr, nullptr, nullptr, nullptr, 0,
        yb, SR + 6*256, NN);
    k_gemm<2,0,1><<<GEMM_GRID, 256, 0, stream>>>(yb, WfPW2, nullptr,
        SR + 6*256, pg1, pb1,
        nullptr, nullptr, nullptr, nullptr, nullptr, nullptr, nullptr, 0,
        zb, SR + 7*256, NN);
    k_poolbn<<<GG, 128, 0, stream>>>(zb, SR + 7*256, pbng, pbnb, goff, out_hgraph, hg);
    // predict
    k_pred1<<<GG, 256, 0, stream>>>(hg, prW1, prb1, ph);
    k_pred2<<<2, 256, 0, stream>>>(ph, prW2, prb2, out_pred);
}

// Round 13
// 563.765 us; speedup vs baseline: 1.2765x; 1.2765x over previous
//
#include <hip/hip_runtime.h>

typedef unsigned short ushort_t;
typedef __attribute__((ext_vector_type(8))) short bf16x8;
typedef __attribute__((ext_vector_type(4))) float f32x4;

#define NN 50000
#define NE 600000
#define DD 128
#define LL 3
#define GG 512
#define NB_SCAN 98   // ceil(NN/512)

__device__ __forceinline__ float b2f(ushort_t u){ return __uint_as_float(((unsigned)u)<<16); }
__device__ __forceinline__ ushort_t f2b(float f){
    unsigned x = __float_as_uint(f);
    return (ushort_t)((x + 0x7fffu + ((x>>16)&1u)) >> 16);
}

// ---- marker for host-side input-layout mismatch (f32 out) ----
__global__ void k_mark(float* __restrict__ out, float val, int n){
    int i = blockIdx.x*256 + threadIdx.x; if (i >= n) return;
    out[i] = (i == 0) ? val : 0.f;
}

// ---- fused setup: wconv + goff + zero cnt + zero SR + layer-0 LUT ----
// [0,180224) wconv | +513 goff | +50000 cnt=0 | +2048 SR=0 | +768 lin0
struct WPtrs { const float* p[11]; };
__global__ void k_setup(WPtrs wp, ushort_t* __restrict__ Wf,
                        const int* __restrict__ bids, int* __restrict__ goff,
                        int* __restrict__ cnt, float* __restrict__ SR,
                        const float* __restrict__ emb, const float* __restrict__ linW,
                        const float* __restrict__ linB, float* __restrict__ yrows){
    int idx = blockIdx.x*256 + threadIdx.x;
    if (idx < 180224){
        int m = idx >> 14, r = idx & 16383;
        int i = r & 7, l2 = (r >> 3) & 63, s = (r >> 9) & 3, n = r >> 11;
        int k   = s*32 + (l2 >> 4)*8 + i;
        int col = n*16 + (l2 & 15);
        Wf[idx] = f2b(wp.p[m][k*DD + col]);
    } else if (idx < 180737){
        int g = idx - 180224;            // 0..512
        int lo = 0, hi = NN;
        while (lo < hi){ int mid = (lo+hi) >> 1; if (bids[mid] < g) lo = mid+1; else hi = mid; }
        goff[g] = lo;
    } else if (idx < 230737){
        cnt[idx - 180737] = 0;
    } else if (idx < 232785){
        SR[idx - 230737] = 0.f;
    } else if (idx < 233553){
        int i = idx - 232785;            // 6*128
        int di = i >> 7, c = i & 127;
        float acc = linB[c];
        for (int k = 0; k < DD; k++) acc = fmaf(emb[di*DD + k], linW[k*DD + c], acc);
        yrows[i] = fmaxf(acc, 0.f);
    }
}

// ---------------- CSR: count (int4) ----------------
__global__ void k_count(const int* __restrict__ dst, int* __restrict__ cnt){
    int e4 = blockIdx.x*256 + threadIdx.x; if (e4 >= NE/4) return;
    int4 dv = ((const int4*)dst)[e4];
    atomicAdd(&cnt[dv.x], 1); atomicAdd(&cnt[dv.y], 1);
    atomicAdd(&cnt[dv.z], 1); atomicAdd(&cnt[dv.w], 1);
}
// ---------------- CSR: multi-block scan ----------------
__global__ void k_scanA(const int* __restrict__ cnt, int* __restrict__ inc, int* __restrict__ bsum){
    __shared__ int s[512];
    int i = blockIdx.x*512 + threadIdx.x;
    int v = (i < NN) ? cnt[i] : 0;
    s[threadIdx.x] = v; __syncthreads();
    for (int off = 1; off < 512; off <<= 1){
        int add = (threadIdx.x >= off) ? s[threadIdx.x - off] : 0;
        __syncthreads();
        s[threadIdx.x] += add;
        __syncthreads();
    }
    if (i < NN) inc[i] = s[threadIdx.x];
    if (threadIdx.x == 511) bsum[blockIdx.x] = s[511];
}
__global__ void k_scanB(const int* __restrict__ bsum, int* __restrict__ boff){
    if (threadIdx.x == 0 && blockIdx.x == 0){
        int acc = 0;
        for (int b = 0; b < NB_SCAN; b++){ boff[b] = acc; acc += bsum[b]; }
        boff[NB_SCAN] = acc;
    }
}
__global__ void k_scanC(const int* __restrict__ cnt, const int* __restrict__ inc,
                        const int* __restrict__ boff, int* __restrict__ rowptr,
                        int* __restrict__ cursor){
    int i = blockIdx.x*512 + threadIdx.x;
    if (i < NN){
        int e = boff[blockIdx.x] + inc[i] - cnt[i];
        rowptr[i] = e; cursor[i] = e;
    } else if (i == NN){
        rowptr[NN] = NE;
    }
}
// ---------------- CSR: fill (int4 loads) ----------------
__global__ void k_fill(const int* __restrict__ src, const int* __restrict__ dst,
                       int* __restrict__ cursor, int* __restrict__ eidx){
    int e4 = blockIdx.x*256 + threadIdx.x; if (e4 >= NE/4) return;
    int4 dv = ((const int4*)dst)[e4];
    int4 sv = ((const int4*)src)[e4];
    int p0 = atomicAdd(&cursor[dv.x], 1); eidx[p0] = sv.x;
    int p1 = atomicAdd(&cursor[dv.y], 1); eidx[p1] = sv.y;
    int p2 = atomicAdd(&cursor[dv.z], 1); eidx[p2] = sv.z;
    int p3 = atomicAdd(&cursor[dv.w], 1); eidx[p3] = sv.w;
}

// ---- layer-0 aggregation from 6-row LUTs (all LDS) ----
__global__ void k_agg0(const int* __restrict__ d, const float* __restrict__ emb,
                       const float* __restrict__ yrows,
                       const int* __restrict__ rowptr, const int* __restrict__ eidx,
                       const float* __restrict__ epsP, ushort_t* __restrict__ zb){
    __shared__ float eL[6*DD], yL[6*DD];
    int t = threadIdx.x;
    for (int i = t; i < 6*DD; i += 256){ eL[i] = emb[i]; yL[i] = yrows[i]; }
    __syncthreads();
    int node = blockIdx.x*16 + (t >> 4);
    if (node >= NN) return;
    int c8 = (t & 15) << 3;
    float epl = 1.0f + epsP[0];
    int dv = d[node]; dv = dv < 0 ? 0 : (dv > 5 ? 5 : dv);
    float a[8];
#pragma unroll
    for (int i = 0; i < 8; i++) a[i] = eL[dv*DD + c8 + i] * epl;
    int e0 = rowptr[node], e1 = rowptr[node+1];
    int e = e0;
    for (; e + 3 < e1; e += 4){
        int s0 = eidx[e], s1 = eidx[e+1], s2 = eidx[e+2], s3 = eidx[e+3];
        int c0 = d[s0], c1 = d[s1], c2 = d[s2], c3 = d[s3];
        c0 = c0 < 0 ? 0 : (c0 > 5 ? 5 : c0);
        c1 = c1 < 0 ? 0 : (c1 > 5 ? 5 : c1);
        c2 = c2 < 0 ? 0 : (c2 > 5 ? 5 : c2);
        c3 = c3 < 0 ? 0 : (c3 > 5 ? 5 : c3);
#pragma unroll
        for (int i = 0; i < 8; i++)
            a[i] += (yL[c0*DD + c8 + i] + yL[c1*DD + c8 + i])
                  + (yL[c2*DD + c8 + i] + yL[c3*DD + c8 + i]);
    }
    for (; e < e1; e++){
        int s = eidx[e];
        int c = d[s]; c = c < 0 ? 0 : (c > 5 ? 5 : c);
#pragma unroll
        for (int i = 0; i < 8; i++) a[i] += yL[c*DD + c8 + i];
    }
    bf16x8 o;
#pragma unroll
    for (int i = 0; i < 8; i++) o[i] = (short)f2b(a[i]);
    *(bf16x8*)(zb + (size_t)node*DD + c8) = o;
}

// ---- aggregation layers>0: 16 lanes/node, unroll x4, BN-from-stats inline ----
__global__ void k_agg(const ushort_t* __restrict__ xb, const ushort_t* __restrict__ yb,
                      ushort_t* __restrict__ zb,
                      const int* __restrict__ rowptr, const int* __restrict__ eidx,
                      const float* __restrict__ epsP, int l,
                      const float* __restrict__ bnstats, const float* __restrict__ bng,
                      const float* __restrict__ bnb){
    int node = blockIdx.x*16 + (threadIdx.x >> 4);
    if (node >= NN) return;
    int c8 = (threadIdx.x & 15) << 3;
    float epl = 1.0f + epsP[l];
    bf16x8 xr = *(const bf16x8*)(xb + (size_t)node*DD + c8);
    float a[8];
#pragma unroll
    for (int i = 0; i < 8; i++){
        int c = c8 + i;
        float mu  = bnstats[c] * (1.0f/NN);
        float var = bnstats[c + DD] * (1.0f/NN) - mu*mu;
        float sc  = rsqrtf(fmaxf(var, 0.f) + 1e-5f) * bng[c];
        float sh  = bnb[c] - mu*sc;
        a[i] = fmaxf(fmaf(b2f((ushort_t)xr[i]), sc, sh), 0.f) * epl;
    }
    int e0 = rowptr[node], e1 = rowptr[node+1];
    int e = e0;
    for (; e + 3 < e1; e += 4){
        int s0 = eidx[e], s1 = eidx[e+1], s2 = eidx[e+2], s3 = eidx[e+3];
        bf16x8 v0 = *(const bf16x8*)(yb + (size_t)s0*DD + c8);
        bf16x8 v1 = *(const bf16x8*)(yb + (size_t)s1*DD + c8);
        bf16x8 v2 = *(const bf16x8*)(yb + (size_t)s2*DD + c8);
        bf16x8 v3 = *(const bf16x8*)(yb + (size_t)s3*DD + c8);
#pragma unroll
        for (int i = 0; i < 8; i++)
            a[i] += (b2f((ushort_t)v0[i]) + b2f((ushort_t)v1[i]))
                  + (b2f((ushort_t)v2[i]) + b2f((ushort_t)v3[i]));
    }
    for (; e < e1; e++){
        int s = eidx[e];
        bf16x8 v = *(const bf16x8*)(yb + (size_t)s*DD + c8);
#pragma unroll
        for (int i = 0; i < 8; i++) a[i] += b2f((ushort_t)v[i]);
    }
    bf16x8 o;
#pragma unroll
    for (int i = 0; i < 8; i++) o[i] = (short)f2b(a[i]);
    *(bf16x8*)(zb + (size_t)node*DD + c8) = o;
}

// ---------------- MFMA GEMM with LDS-repacked coalesced epilogue ----------------
template<int AMODE, int OMODE, int STATS>
__global__ __launch_bounds__(256) void k_gemm(
    const ushort_t* __restrict__ A, const ushort_t* __restrict__ Wf,
    const float* __restrict__ bias,
    const float* __restrict__ bnstats, const float* __restrict__ bng,
    const float* __restrict__ bnb,
    ushort_t* __restrict__ C, float* __restrict__ stats_out, int M)
{
    __shared__ float ssl[256];
    __shared__ float sred[256];
    __shared__ float lrep[64*132];
    const int t = threadIdx.x;
    const int w = t >> 6, l = t & 63;
    const int rowBlk = blockIdx.x*64, rowBase = rowBlk + w*16;
    const int lm = l & 15, kg = l >> 4;

    if (AMODE == 2 && t < 128){
        float mu  = bnstats[t] * (1.0f/NN);
        float var = bnstats[t + DD] * (1.0f/NN) - mu*mu;
        float sc  = rsqrtf(fmaxf(var, 0.f) + 1e-5f) * bng[t];
        ssl[t] = sc;
        ssl[t + DD] = bnb[t] - mu*sc;
    }
    if (STATS) sred[t] = 0.f;
    if (AMODE == 2 || STATS) __syncthreads();

    f32x4 acc[8];
#pragma unroll
    for (int n = 0; n < 8; n++) acc[n] = (f32x4){0.f,0.f,0.f,0.f};

    int arow = rowBase + lm;
    if (arow >= M) arow = M - 1;
    const ushort_t* aptr = A + (size_t)arow*DD + kg*8;

#pragma unroll
    for (int s = 0; s < 4; s++){
        bf16x8 af;
        if (AMODE == 0){
            af = *(const bf16x8*)(aptr + s*32);
        } else {
            bf16x8 ar = *(const bf16x8*)(aptr + s*32);
            int k0 = s*32 + kg*8;
#pragma unroll
            for (int i = 0; i < 8; i++){
                float v = b2f((ushort_t)ar[i]);
                v = fmaxf(fmaf(v, ssl[k0+i], ssl[DD+k0+i]), 0.f);
                ((ushort_t*)&af)[i] = f2b(v);
            }
        }
#pragma unroll
        for (int n = 0; n < 8; n++){
            bf16x8 bfr = *(const bf16x8*)(Wf + (size_t)((n*4 + s)*64 + l)*8);
            acc[n] = __builtin_amdgcn_mfma_f32_16x16x32_bf16(af, bfr, acc[n], 0, 0, 0);
        }
    }

#pragma unroll
    for (int n = 0; n < 8; n++){
        int col = n*16 + lm;
        float cs = 0.f, cq = 0.f;
#pragma unroll
        for (int j = 0; j < 4; j++){
            float v = acc[n][j];
            if (OMODE == 1) v = fmaxf(v + bias[col], 0.f);
            lrep[(w*16 + kg*4 + j)*132 + col] = v;
            if (STATS && (rowBase + kg*4 + j) < M){ cs += v; cq += v*v; }
        }
        if (STATS){
            cs += __shfl_xor(cs, 16); cs += __shfl_xor(cs, 32);
            cq += __shfl_xor(cq, 16); cq += __shfl_xor(cq, 32);
            if (kg == 0){
                atomicAdd(&sred[col], cs);
                atomicAdd(&sred[col + DD], cq);
            }
        }
    }
    __syncthreads();

    {
        int lr = t & 63;
        int gr = rowBlk + lr;
        if (gr < M){
            int seg = (t >> 6) * 32;
            const float* lp = lrep + lr*132 + seg;
            bf16x8 o0, o1, o2, o3;
#pragma unroll
            for (int i = 0; i < 8; i++){
                o0[i] = (short)f2b(lp[i]);
                o1[i] = (short)f2b(lp[8+i]);
                o2[i] = (short)f2b(lp[16+i]);
                o3[i] = (short)f2b(lp[24+i]);
            }
            ushort_t* cp = C + (size_t)gr*DD + seg;
            *(bf16x8*)(cp)      = o0;
            *(bf16x8*)(cp + 8)  = o1;
            *(bf16x8*)(cp + 16) = o2;
            *(bf16x8*)(cp + 24) = o3;
        }
    }

    if (STATS){
        __syncthreads();
        atomicAdd(&stats_out[t], sred[t]);
    }
}

// ---------------- pooling with inline BN+ReLU (bf16 in, f32 out) ----------------
__global__ void k_poolbn(const ushort_t* __restrict__ h,
                         const float* __restrict__ bnstats, const float* __restrict__ bng,
                         const float* __restrict__ bnb,
                         const int* __restrict__ goff, float* __restrict__ outp,
                         float* __restrict__ outf){
    int g = blockIdx.x;
    int c = threadIdx.x;           // 128 threads
    float mu  = bnstats[c] * (1.0f/NN);
    float var = bnstats[c + DD] * (1.0f/NN) - mu*mu;
    float sc  = rsqrtf(fmaxf(var, 0.f) + 1e-5f) * bng[c];
    float sh  = bnb[c] - mu*sc;
    int r0 = goff[g], r1 = goff[g+1];
    float acc = 0.f;
    for (int r = r0; r < r1; r++)
        acc += fmaxf(fmaf(b2f(h[(size_t)r*DD + c]), sc, sh), 0.f);
    float m = acc / fmaxf((float)(r1 - r0), 1.0f);
    outp[g*DD + c] = m;
    if (outf) outf[g*DD + c] = m;
}

// ---------------- fused predict head: block g -> out[g] ----------------
__global__ __launch_bounds__(256) void k_pred(const float* __restrict__ hg,
                        const float* __restrict__ W1, const float* __restrict__ b1,
                        const float* __restrict__ W2, const float* __restrict__ b2,
                        float* __restrict__ out){
    __shared__ float hrow[DD];
    __shared__ float pr[256];
    int g = blockIdx.x, t = threadIdx.x;
    if (t < DD) hrow[t] = hg[g*DD + t];
    __syncthreads();
    float acc = b1[t];
    for (int k = 0; k < DD; k++) acc = fmaf(hrow[k], W1[k*256 + t], acc);
    pr[t] = fmaxf(acc, 0.f) * W2[t];
    __syncthreads();
    for (int off = 128; off > 0; off >>= 1){
        if (t < off) pr[t] += pr[t + off];
        __syncthreads();
    }
    if (t == 0) out[g] = pr[0] + b2[0];
}

extern "C" void kernel_launch(void* const* d_in, const int* in_sizes, int n_in,
                              void* d_out, int out_size, void* d_ws, size_t ws_size,
                              hipStream_t stream){
    float* out = (float*)d_out;
    const int OUT_N = GG + GG*DD + LL*GG*DD;      // 262656

    static const int EXP[24] = {50000,600000,600000,50000, 768,49152,384,49152,384,384,
                                49152,3,384,384,16384,128,128,16384,128,128,
                                32768,256,256,1};
    int bad = -1;
    if (n_in != 24) bad = 50;
    else for (int i = 0; i < 24; i++) if (in_sizes[i] != EXP[i]) { bad = i; break; }
    if (bad >= 0){
        k_mark<<<(OUT_N+255)/256, 256, 0, stream>>>(out, 2048.0f + (float)bad, OUT_N);
        return;
    }

    const int* d    = (const int*)d_in[0];
    const int* src  = (const int*)d_in[1];
    const int* dst  = (const int*)d_in[2];
    const int* bids = (const int*)d_in[3];
    const float* emb  = (const float*)d_in[4];
    const float* linW = (const float*)d_in[5];
    const float* linB = (const float*)d_in[6];
    const float* W1   = (const float*)d_in[7];
    const float* g1   = (const float*)d_in[8];
    const float* b1   = (const float*)d_in[9];
    const float* W2   = (const float*)d_in[10];
    const float* epsA = (const float*)d_in[11];
    const float* bng  = (const float*)d_in[12];
    const float* bnb  = (const float*)d_in[13];
    const float* pW1  = (const float*)d_in[14];
    const float* pg1  = (const float*)d_in[15];
    const float* pb1  = (const float*)d_in[16];
    const float* pW2  = (const float*)d_in[17];
    const float* pbng = (const float*)d_in[18];
    const float* pbnb = (const float*)d_in[19];
    const float* prW1 = (const float*)d_in[20];
    const float* prb1 = (const float*)d_in[21];
    const float* prW2 = (const float*)d_in[22];
    const float* prb2 = (const float*)d_in[23];

    // ---- workspace (~45 MB) ----
    ushort_t* xb  = (ushort_t*)d_ws;
    ushort_t* yb  = xb + (size_t)NN*DD;
    ushort_t* zb  = yb + (size_t)NN*DD;
    ushort_t* Wf  = zb + (size_t)NN*DD;           // 11*16384 bf16
    float* SR    = (float*)(Wf + 11*16384);       // 8*256
    float* yrows = SR + 8*256;                    // 6*128
    float* hg    = yrows + 6*DD;                  // GG*DD
    int* cnt    = (int*)(hg + (size_t)GG*DD);
    int* inc    = cnt + NN;
    int* rowptr = inc + NN;                       // N+1
    int* cursor = rowptr + NN + 1;
    int* eidx   = cursor + NN;                    // E
    int* goff   = eidx + NE;                      // G+1
    int* bsum   = goff + GG + 1;
    int* boff   = bsum + NB_SCAN;

    float* out_pred   = out;
    float* out_hgraph = out + GG;
    float* out_hmeans = out + GG + GG*DD;

    const int GEMM_GRID = (NN + 63)/64;           // 782
    const int AGG_GRID  = (NN + 15)/16;           // 3125
    const int E4_GRID   = (NE/4 + 255)/256;       // 586
    const int SETUP_GRID= (233553 + 255)/256;     // 913

    WPtrs wp;
    for (int i = 0; i < 3; i++){
        wp.p[i]   = linW + (size_t)i*DD*DD;
        wp.p[3+i] = W1   + (size_t)i*DD*DD;
        wp.p[6+i] = W2   + (size_t)i*DD*DD;
    }
    wp.p[9] = pW1; wp.p[10] = pW2;
    const ushort_t* WfLin = Wf;
    const ushort_t* WfW1  = Wf + 3*16384;
    const ushort_t* WfW2  = Wf + 6*16384;
    const ushort_t* WfPW1 = Wf + 9*16384;
    const ushort_t* WfPW2 = Wf + 10*16384;

    // setup + CSR
    k_setup<<<SETUP_GRID, 256, 0, stream>>>(wp, Wf, bids, goff, cnt, SR, emb, linW, linB, yrows);
    k_count<<<E4_GRID, 256, 0, stream>>>(dst, cnt);
    k_scanA<<<NB_SCAN, 512, 0, stream>>>(cnt, inc, bsum);
    k_scanB<<<1, 64, 0, stream>>>(bsum, boff);
    k_scanC<<<NB_SCAN, 512, 0, stream>>>(cnt, inc, boff, rowptr, cursor);
    k_fill<<<E4_GRID, 256, 0, stream>>>(src, dst, cursor, eidx);

    // ---- layer 0 (LUT aggregation) ----
    k_agg0<<<AGG_GRID, 256, 0, stream>>>(d, emb, yrows, rowptr, eidx, epsA, zb);
    k_gemm<0,0,1><<<GEMM_GRID, 256, 0, stream>>>(zb, WfW1, nullptr, nullptr, nullptr, nullptr, yb, SR + 0*256, NN);
    k_gemm<2,0,1><<<GEMM_GRID, 256, 0, stream>>>(yb, WfW2, nullptr, SR + 0*256, g1, b1, xb, SR + 1*256, NN);
    k_poolbn<<<GG, 128, 0, stream>>>(xb, SR + 1*256, bng, bnb, goff, out_hmeans, nullptr);

    // ---- layers 1,2 ----
    for (int l = 1; l < LL; l++){
        const float* pstat = SR + (2*l - 1)*256;
        const float* pg    = bng + (size_t)(l-1)*DD;
        const float* pb    = bnb + (size_t)(l-1)*DD;
        float* statsIn  = SR + (2*l)*256;
        float* statsOut = SR + (2*l + 1)*256;

        k_gemm<2,1,0><<<GEMM_GRID, 256, 0, stream>>>(xb, WfLin + (size_t)l*16384, linB + (size_t)l*DD, pstat, pg, pb, yb, nullptr, NN);
        k_agg<<<AGG_GRID, 256, 0, stream>>>(xb, yb, zb, rowptr, eidx, epsA, l, pstat, pg, pb);
        k_gemm<0,0,1><<<GEMM_GRID, 256, 0, stream>>>(zb, WfW1 + (size_t)l*16384, nullptr, nullptr, nullptr, nullptr, yb, statsIn, NN);
        k_gemm<2,0,1><<<GEMM_GRID, 256, 0, stream>>>(yb, WfW2 + (size_t)l*16384, nullptr, statsIn, g1 + (size_t)l*DD, b1 + (size_t)l*DD, xb, statsOut, NN);
        k_poolbn<<<GG, 128, 0, stream>>>(xb, statsOut, bng + (size_t)l*DD, bnb + (size_t)l*DD, goff, out_hmeans + (size_t)l*GG*DD, nullptr);
    }

    // ---- pooling MLP ----
    k_gemm<2,0,1><<<GEMM_GRID, 256, 0, stream>>>(xb, WfPW1, nullptr, SR + 5*256, bng + 2*DD, bnb + 2*DD, yb, SR + 6*256, NN);
    k_gemm<2,0,1><<<GEMM_GRID, 256, 0, stream>>>(yb, WfPW2, nullptr, SR + 6*256, pg1, pb1, zb, SR + 7*256, NN);
    k_poolbn<<<GG, 128, 0, stream>>>(zb, SR + 7*256, pbng, pbnb, goff, out_hgraph, hg);
    // predict (fused)
    k_pred<<<GG, 256, 0, stream>>>(hg, prW1, prb1, prW2, prb2, out_pred);
}

// Round 14
// 484.008 us; speedup vs baseline: 1.4869x; 1.1648x over previous
//
#include <hip/hip_runtime.h>

typedef unsigned short ushort_t;
typedef __attribute__((ext_vector_type(8))) short bf16x8;
typedef __attribute__((ext_vector_type(4))) float f32x4;

#define NN 50000
#define NE 600000
#define DD 128
#define LL 3
#define GG 512
#define NB_SCAN 98   // ceil(NN/512)
#define GGRID 782    // ceil(NN/64) gemm blocks

__device__ __forceinline__ float b2f(ushort_t u){ return __uint_as_float(((unsigned)u)<<16); }
__device__ __forceinline__ ushort_t f2b(float f){
    unsigned x = __float_as_uint(f);
    return (ushort_t)((x + 0x7fffu + ((x>>16)&1u)) >> 16);
}

// ---- marker for host-side input-layout mismatch (f32 out) ----
__global__ void k_mark(float* __restrict__ out, float val, int n){
    int i = blockIdx.x*256 + threadIdx.x; if (i >= n) return;
    out[i] = (i == 0) ? val : 0.f;
}

// ---- fused setup: wconv + goff + zero cnt + zero SR + layer-0 LUT ----
struct WPtrs { const float* p[11]; };
__global__ void k_setup(WPtrs wp, ushort_t* __restrict__ Wf,
                        const int* __restrict__ bids, int* __restrict__ goff,
                        int* __restrict__ cnt, float* __restrict__ SR,
                        const float* __restrict__ emb, const float* __restrict__ linW,
                        const float* __restrict__ linB, float* __restrict__ yrows){
    int idx = blockIdx.x*256 + threadIdx.x;
    if (idx < 180224){
        int m = idx >> 14, r = idx & 16383;
        int i = r & 7, l2 = (r >> 3) & 63, s = (r >> 9) & 3, n = r >> 11;
        int k   = s*32 + (l2 >> 4)*8 + i;
        int col = n*16 + (l2 & 15);
        Wf[idx] = f2b(wp.p[m][k*DD + col]);
    } else if (idx < 180737){
        int g = idx - 180224;            // 0..512
        int lo = 0, hi = NN;
        while (lo < hi){ int mid = (lo+hi) >> 1; if (bids[mid] < g) lo = mid+1; else hi = mid; }
        goff[g] = lo;
    } else if (idx < 230737){
        cnt[idx - 180737] = 0;
    } else if (idx < 232785){
        SR[idx - 230737] = 0.f;
    } else if (idx < 233553){
        int i = idx - 232785;            // 6*128
        int di = i >> 7, c = i & 127;
        float acc = linB[c];
        for (int k = 0; k < DD; k++) acc = fmaf(emb[di*DD + k], linW[k*DD + c], acc);
        yrows[i] = fmaxf(acc, 0.f);
    }
}

// ---------------- CSR: count (int4) ----------------
__global__ void k_count(const int* __restrict__ dst, int* __restrict__ cnt){
    int e4 = blockIdx.x*256 + threadIdx.x; if (e4 >= NE/4) return;
    int4 dv = ((const int4*)dst)[e4];
    atomicAdd(&cnt[dv.x], 1); atomicAdd(&cnt[dv.y], 1);
    atomicAdd(&cnt[dv.z], 1); atomicAdd(&cnt[dv.w], 1);
}
// ---------------- CSR: multi-block scan ----------------
__global__ void k_scanA(const int* __restrict__ cnt, int* __restrict__ inc, int* __restrict__ bsum){
    __shared__ int s[512];
    int i = blockIdx.x*512 + threadIdx.x;
    int v = (i < NN) ? cnt[i] : 0;
    s[threadIdx.x] = v; __syncthreads();
    for (int off = 1; off < 512; off <<= 1){
        int add = (threadIdx.x >= off) ? s[threadIdx.x - off] : 0;
        __syncthreads();
        s[threadIdx.x] += add;
        __syncthreads();
    }
    if (i < NN) inc[i] = s[threadIdx.x];
    if (threadIdx.x == 511) bsum[blockIdx.x] = s[511];
}
__global__ void k_scanB(const int* __restrict__ bsum, int* __restrict__ boff){
    __shared__ int s[128];
    int t = threadIdx.x;                  // 128
    int v = (t < NB_SCAN) ? bsum[t] : 0;
    s[t] = v; __syncthreads();
    for (int off = 1; off < 128; off <<= 1){
        int a = (t >= off) ? s[t - off] : 0;
        __syncthreads();
        s[t] += a;
        __syncthreads();
    }
    if (t < NB_SCAN) boff[t] = s[t] - v;
    if (t == NB_SCAN - 1) boff[NB_SCAN] = s[t];
}
__global__ void k_scanC(const int* __restrict__ cnt, const int* __restrict__ inc,
                        const int* __restrict__ boff, int* __restrict__ rowptr,
                        int* __restrict__ cursor){
    int i = blockIdx.x*512 + threadIdx.x;
    if (i < NN){
        int e = boff[blockIdx.x] + inc[i] - cnt[i];
        rowptr[i] = e; cursor[i] = e;
    } else if (i == NN){
        rowptr[NN] = NE;
    }
}
// ---------------- CSR: fill (int4 loads) ----------------
__global__ void k_fill(const int* __restrict__ src, const int* __restrict__ dst,
                       int* __restrict__ cursor, int* __restrict__ eidx){
    int e4 = blockIdx.x*256 + threadIdx.x; if (e4 >= NE/4) return;
    int4 dv = ((const int4*)dst)[e4];
    int4 sv = ((const int4*)src)[e4];
    int p0 = atomicAdd(&cursor[dv.x], 1); eidx[p0] = sv.x;
    int p1 = atomicAdd(&cursor[dv.y], 1); eidx[p1] = sv.y;
    int p2 = atomicAdd(&cursor[dv.z], 1); eidx[p2] = sv.z;
    int p3 = atomicAdd(&cursor[dv.w], 1); eidx[p3] = sv.w;
}

// ---- layer-0 aggregation from 6-row LUTs (all LDS) ----
__global__ void k_agg0(const int* __restrict__ d, const float* __restrict__ emb,
                       const float* __restrict__ yrows,
                       const int* __restrict__ rowptr, const int* __restrict__ eidx,
                       const float* __restrict__ epsP, ushort_t* __restrict__ zb){
    __shared__ float eL[6*DD], yL[6*DD];
    int t = threadIdx.x;
    for (int i = t; i < 6*DD; i += 256){ eL[i] = emb[i]; yL[i] = yrows[i]; }
    __syncthreads();
    int node = blockIdx.x*16 + (t >> 4);
    if (node >= NN) return;
    int c8 = (t & 15) << 3;
    float epl = 1.0f + epsP[0];
    int dv = d[node]; dv = dv < 0 ? 0 : (dv > 5 ? 5 : dv);
    float a[8];
#pragma unroll
    for (int i = 0; i < 8; i++) a[i] = eL[dv*DD + c8 + i] * epl;
    int e0 = rowptr[node], e1 = rowptr[node+1];
    int e = e0;
    for (; e + 3 < e1; e += 4){
        int s0 = eidx[e], s1 = eidx[e+1], s2 = eidx[e+2], s3 = eidx[e+3];
        int c0 = d[s0], c1 = d[s1], c2 = d[s2], c3 = d[s3];
        c0 = c0 < 0 ? 0 : (c0 > 5 ? 5 : c0);
        c1 = c1 < 0 ? 0 : (c1 > 5 ? 5 : c1);
        c2 = c2 < 0 ? 0 : (c2 > 5 ? 5 : c2);
        c3 = c3 < 0 ? 0 : (c3 > 5 ? 5 : c3);
#pragma unroll
        for (int i = 0; i < 8; i++)
            a[i] += (yL[c0*DD + c8 + i] + yL[c1*DD + c8 + i])
                  + (yL[c2*DD + c8 + i] + yL[c3*DD + c8 + i]);
    }
    for (; e < e1; e++){
        int s = eidx[e];
        int c = d[s]; c = c < 0 ? 0 : (c > 5 ? 5 : c);
#pragma unroll
        for (int i = 0; i < 8; i++) a[i] += yL[c*DD + c8 + i];
    }
    bf16x8 o;
#pragma unroll
    for (int i = 0; i < 8; i++) o[i] = (short)f2b(a[i]);
    *(bf16x8*)(zb + (size_t)node*DD + c8) = o;
}

// ---- aggregation layers>0 ----
__global__ void k_agg(const ushort_t* __restrict__ xb, const ushort_t* __restrict__ yb,
                      ushort_t* __restrict__ zb,
                      const int* __restrict__ rowptr, const int* __restrict__ eidx,
                      const float* __restrict__ epsP, int l,
                      const float* __restrict__ bnstats, const float* __restrict__ bng,
                      const float* __restrict__ bnb){
    int node = blockIdx.x*16 + (threadIdx.x >> 4);
    if (node >= NN) return;
    int c8 = (threadIdx.x & 15) << 3;
    float epl = 1.0f + epsP[l];
    bf16x8 xr = *(const bf16x8*)(xb + (size_t)node*DD + c8);
    float a[8];
#pragma unroll
    for (int i = 0; i < 8; i++){
        int c = c8 + i;
        float mu  = bnstats[c] * (1.0f/NN);
        float var = bnstats[c + DD] * (1.0f/NN) - mu*mu;
        float sc  = rsqrtf(fmaxf(var, 0.f) + 1e-5f) * bng[c];
        float sh  = bnb[c] - mu*sc;
        a[i] = fmaxf(fmaf(b2f((ushort_t)xr[i]), sc, sh), 0.f) * epl;
    }
    int e0 = rowptr[node], e1 = rowptr[node+1];
    int e = e0;
    for (; e + 3 < e1; e += 4){
        int s0 = eidx[e], s1 = eidx[e+1], s2 = eidx[e+2], s3 = eidx[e+3];
        bf16x8 v0 = *(const bf16x8*)(yb + (size_t)s0*DD + c8);
        bf16x8 v1 = *(const bf16x8*)(yb + (size_t)s1*DD + c8);
        bf16x8 v2 = *(const bf16x8*)(yb + (size_t)s2*DD + c8);
        bf16x8 v3 = *(const bf16x8*)(yb + (size_t)s3*DD + c8);
#pragma unroll
        for (int i = 0; i < 8; i++)
            a[i] += (b2f((ushort_t)v0[i]) + b2f((ushort_t)v1[i]))
                  + (b2f((ushort_t)v2[i]) + b2f((ushort_t)v3[i]));
    }
    for (; e < e1; e++){
        int s = eidx[e];
        bf16x8 v = *(const bf16x8*)(yb + (size_t)s*DD + c8);
#pragma unroll
        for (int i = 0; i < 8; i++) a[i] += b2f((ushort_t)v[i]);
    }
    bf16x8 o;
#pragma unroll
    for (int i = 0; i < 8; i++) o[i] = (short)f2b(a[i]);
    *(bf16x8*)(zb + (size_t)node*DD + c8) = o;
}

// ---------------- MFMA GEMM + optional fused graph-pool blocks ----------------
// AMODE 2: A'=relu(bn(A)) (stats/g/b shared with fused pool).  OMODE 1: relu(C+bias).
// STATS: column sum/sumsq -> stats_out.  POOL: blocks >= GGRID pool mean_g relu(bn(A)).
template<int AMODE, int OMODE, int STATS, int POOL>
__global__ __launch_bounds__(256) void k_gemm(
    const ushort_t* __restrict__ A, const ushort_t* __restrict__ Wf,
    const float* __restrict__ bias,
    const float* __restrict__ bnstats, const float* __restrict__ bng,
    const float* __restrict__ bnb,
    ushort_t* __restrict__ C, float* __restrict__ stats_out,
    const int* __restrict__ goff, float* __restrict__ pool_out, int M)
{
    __shared__ float ssl[256];
    __shared__ float sred[256];
    __shared__ float lrep[64*132];
    const int t = threadIdx.x;

    if (POOL && blockIdx.x >= GGRID){
        int g = blockIdx.x - GGRID;
        int c = t & 127, hf = t >> 7;
        float mu  = bnstats[c] * (1.0f/NN);
        float var = bnstats[c + DD] * (1.0f/NN) - mu*mu;
        float sc  = rsqrtf(fmaxf(var, 0.f) + 1e-5f) * bng[c];
        float sh  = bnb[c] - mu*sc;
        int r0 = goff[g], r1 = goff[g+1];
        float acc = 0.f;
        for (int r = r0 + hf; r < r1; r += 2)
            acc += fmaxf(fmaf(b2f(A[(size_t)r*DD + c]), sc, sh), 0.f);
        sred[t] = acc; __syncthreads();
        if (t < 128)
            pool_out[g*DD + t] = (sred[t] + sred[t+128]) / fmaxf((float)(r1 - r0), 1.0f);
        return;
    }

    const int w = t >> 6, l = t & 63;
    const int rowBlk = blockIdx.x*64, rowBase = rowBlk + w*16;
    const int lm = l & 15, kg = l >> 4;

    if (AMODE == 2 && t < 128){
        float mu  = bnstats[t] * (1.0f/NN);
        float var = bnstats[t + DD] * (1.0f/NN) - mu*mu;
        float sc  = rsqrtf(fmaxf(var, 0.f) + 1e-5f) * bng[t];
        ssl[t] = sc;
        ssl[t + DD] = bnb[t] - mu*sc;
    }
    if (STATS) sred[t] = 0.f;
    if (AMODE == 2 || STATS) __syncthreads();

    f32x4 acc[8];
#pragma unroll
    for (int n = 0; n < 8; n++) acc[n] = (f32x4){0.f,0.f,0.f,0.f};

    int arow = rowBase + lm;
    if (arow >= M) arow = M - 1;
    const ushort_t* aptr = A + (size_t)arow*DD + kg*8;

#pragma unroll
    for (int s = 0; s < 4; s++){
        bf16x8 af;
        if (AMODE == 0){
            af = *(const bf16x8*)(aptr + s*32);
        } else {
            bf16x8 ar = *(const bf16x8*)(aptr + s*32);
            int k0 = s*32 + kg*8;
#pragma unroll
            for (int i = 0; i < 8; i++){
                float v = b2f((ushort_t)ar[i]);
                v = fmaxf(fmaf(v, ssl[k0+i], ssl[DD+k0+i]), 0.f);
                ((ushort_t*)&af)[i] = f2b(v);
            }
        }
#pragma unroll
        for (int n = 0; n < 8; n++){
            bf16x8 bfr = *(const bf16x8*)(Wf + (size_t)((n*4 + s)*64 + l)*8);
            acc[n] = __builtin_amdgcn_mfma_f32_16x16x32_bf16(af, bfr, acc[n], 0, 0, 0);
        }
    }

#pragma unroll
    for (int n = 0; n < 8; n++){
        int col = n*16 + lm;
        float cs = 0.f, cq = 0.f;
#pragma unroll
        for (int j = 0; j < 4; j++){
            float v = acc[n][j];
            if (OMODE == 1) v = fmaxf(v + bias[col], 0.f);
            lrep[(w*16 + kg*4 + j)*132 + col] = v;
            if (STATS && (rowBase + kg*4 + j) < M){ cs += v; cq += v*v; }
        }
        if (STATS){
            cs += __shfl_xor(cs, 16); cs += __shfl_xor(cs, 32);
            cq += __shfl_xor(cq, 16); cq += __shfl_xor(cq, 32);
            if (kg == 0){
                atomicAdd(&sred[col], cs);
                atomicAdd(&sred[col + DD], cq);
            }
        }
    }
    __syncthreads();

    {
        int lr = t & 63;
        int gr = rowBlk + lr;
        if (gr < M){
            int seg = (t >> 6) * 32;
            const float* lp = lrep + lr*132 + seg;
            bf16x8 o0, o1, o2, o3;
#pragma unroll
            for (int i = 0; i < 8; i++){
                o0[i] = (short)f2b(lp[i]);
                o1[i] = (short)f2b(lp[8+i]);
                o2[i] = (short)f2b(lp[16+i]);
                o3[i] = (short)f2b(lp[24+i]);
            }
            ushort_t* cp = C + (size_t)gr*DD + seg;
            *(bf16x8*)(cp)      = o0;
            *(bf16x8*)(cp + 8)  = o1;
            *(bf16x8*)(cp + 16) = o2;
            *(bf16x8*)(cp + 24) = o3;
        }
    }

    if (STATS){
        __syncthreads();
        atomicAdd(&stats_out[t], sred[t]);
    }
}

// ---------------- fused h_graph pool + predict head: block g -> out ----------------
__global__ __launch_bounds__(256) void k_poolpred(const ushort_t* __restrict__ zb,
        const float* __restrict__ bnstats, const float* __restrict__ bng,
        const float* __restrict__ bnb, const int* __restrict__ goff,
        const float* __restrict__ W1, const float* __restrict__ b1,
        const float* __restrict__ W2, const float* __restrict__ b2,
        float* __restrict__ out_hgraph, float* __restrict__ out_pred){
    __shared__ float hrow[DD];
    __shared__ float pr[256];
    int g = blockIdx.x, t = threadIdx.x;
    int c = t & 127, hf = t >> 7;
    float mu  = bnstats[c] * (1.0f/NN);
    float var = bnstats[c + DD] * (1.0f/NN) - mu*mu;
    float sc  = rsqrtf(fmaxf(var, 0.f) + 1e-5f) * bng[c];
    float sh  = bnb[c] - mu*sc;
    int r0 = goff[g], r1 = goff[g+1];
    float acc = 0.f;
    for (int r = r0 + hf; r < r1; r += 2)
        acc += fmaxf(fmaf(b2f(zb[(size_t)r*DD + c]), sc, sh), 0.f);
    pr[t] = acc; __syncthreads();
    if (t < 128){
        float m = (pr[t] + pr[t+128]) / fmaxf((float)(r1 - r0), 1.0f);
        hrow[t] = m;
        out_hgraph[g*DD + t] = m;
    }
    __syncthreads();
    float a2 = b1[t];
    for (int k = 0; k < DD; k++) a2 = fmaf(hrow[k], W1[k*256 + t], a2);
    pr[t] = fmaxf(a2, 0.f) * W2[t];
    __syncthreads();
    for (int off = 128; off > 0; off >>= 1){
        if (t < off) pr[t] += pr[t + off];
        __syncthreads();
    }
    if (t == 0) out_pred[g] = pr[0] + b2[0];
}

extern "C" void kernel_launch(void* const* d_in, const int* in_sizes, int n_in,
                              void* d_out, int out_size, void* d_ws, size_t ws_size,
                              hipStream_t stream){
    float* out = (float*)d_out;
    const int OUT_N = GG + GG*DD + LL*GG*DD;      // 262656

    static const int EXP[24] = {50000,600000,600000,50000, 768,49152,384,49152,384,384,
                                49152,3,384,384,16384,128,128,16384,128,128,
                                32768,256,256,1};
    int bad = -1;
    if (n_in != 24) bad = 50;
    else for (int i = 0; i < 24; i++) if (in_sizes[i] != EXP[i]) { bad = i; break; }
    if (bad >= 0){
        k_mark<<<(OUT_N+255)/256, 256, 0, stream>>>(out, 2048.0f + (float)bad, OUT_N);
        return;
    }

    const int* d    = (const int*)d_in[0];
    const int* src  = (const int*)d_in[1];
    const int* dst  = (const int*)d_in[2];
    const int* bids = (const int*)d_in[3];
    const float* emb  = (const float*)d_in[4];
    const float* linW = (const float*)d_in[5];
    const float* linB = (const float*)d_in[6];
    const float* W1   = (const float*)d_in[7];
    const float* g1   = (const float*)d_in[8];
    const float* b1   = (const float*)d_in[9];
    const float* W2   = (const float*)d_in[10];
    const float* epsA = (const float*)d_in[11];
    const float* bng  = (const float*)d_in[12];
    const float* bnb  = (const float*)d_in[13];
    const float* pW1  = (const float*)d_in[14];
    const float* pg1  = (const float*)d_in[15];
    const float* pb1  = (const float*)d_in[16];
    const float* pW2  = (const float*)d_in[17];
    const float* pbng = (const float*)d_in[18];
    const float* pbnb = (const float*)d_in[19];
    const float* prW1 = (const float*)d_in[20];
    const float* prb1 = (const float*)d_in[21];
    const float* prW2 = (const float*)d_in[22];
    const float* prb2 = (const float*)d_in[23];

    // ---- workspace (~45 MB) ----
    ushort_t* xb  = (ushort_t*)d_ws;
    ushort_t* yb  = xb + (size_t)NN*DD;
    ushort_t* zb  = yb + (size_t)NN*DD;
    ushort_t* Wf  = zb + (size_t)NN*DD;           // 11*16384 bf16
    float* SR    = (float*)(Wf + 11*16384);       // 8*256
    float* yrows = SR + 8*256;                    // 6*128
    int* cnt    = (int*)(yrows + 6*DD);
    int* inc    = cnt + NN;
    int* rowptr = inc + NN;                       // N+1
    int* cursor = rowptr + NN + 1;
    int* eidx   = cursor + NN;                    // E
    int* goff   = eidx + NE;                      // G+1
    int* bsum   = goff + GG + 1;
    int* boff   = bsum + NB_SCAN;

    float* out_pred   = out;
    float* out_hgraph = out + GG;
    float* out_hmeans = out + GG + GG*DD;

    const int AGG_GRID  = (NN + 15)/16;           // 3125
    const int E4_GRID   = (NE/4 + 255)/256;       // 586
    const int SETUP_GRID= (233553 + 255)/256;     // 913
    const int GP_GRID   = GGRID + GG;             // 1294 (gemm + fused pool)

    WPtrs wp;
    for (int i = 0; i < 3; i++){
        wp.p[i]   = linW + (size_t)i*DD*DD;
        wp.p[3+i] = W1   + (size_t)i*DD*DD;
        wp.p[6+i] = W2   + (size_t)i*DD*DD;
    }
    wp.p[9] = pW1; wp.p[10] = pW2;
    const ushort_t* WfLin = Wf;
    const ushort_t* WfW1  = Wf + 3*16384;
    const ushort_t* WfW2  = Wf + 6*16384;
    const ushort_t* WfPW1 = Wf + 9*16384;
    const ushort_t* WfPW2 = Wf + 10*16384;

    // setup + CSR
    k_setup<<<SETUP_GRID, 256, 0, stream>>>(wp, Wf, bids, goff, cnt, SR, emb, linW, linB, yrows);
    k_count<<<E4_GRID, 256, 0, stream>>>(dst, cnt);
    k_scanA<<<NB_SCAN, 512, 0, stream>>>(cnt, inc, bsum);
    k_scanB<<<1, 128, 0, stream>>>(bsum, boff);
    k_scanC<<<NB_SCAN, 512, 0, stream>>>(cnt, inc, boff, rowptr, cursor);
    k_fill<<<E4_GRID, 256, 0, stream>>>(src, dst, cursor, eidx);

    // ---- layer 0 ----
    k_agg0<<<AGG_GRID, 256, 0, stream>>>(d, emb, yrows, rowptr, eidx, epsA, zb);
    k_gemm<0,0,1,0><<<GGRID, 256, 0, stream>>>(zb, WfW1, nullptr, nullptr, nullptr, nullptr,
        yb, SR + 0*256, nullptr, nullptr, NN);
    k_gemm<2,0,1,0><<<GGRID, 256, 0, stream>>>(yb, WfW2, nullptr, SR + 0*256, g1, b1,
        xb, SR + 1*256, nullptr, nullptr, NN);

    // ---- layers 1,2 (lin-GEMM carries previous layer's h_means pool) ----
    for (int l = 1; l < LL; l++){
        const float* pstat = SR + (2*l - 1)*256;
        const float* pg    = bng + (size_t)(l-1)*DD;
        const float* pb    = bnb + (size_t)(l-1)*DD;
        float* statsIn  = SR + (2*l)*256;
        float* statsOut = SR + (2*l + 1)*256;

        k_gemm<2,1,0,1><<<GP_GRID, 256, 0, stream>>>(xb, WfLin + (size_t)l*16384,
            linB + (size_t)l*DD, pstat, pg, pb,
            yb, nullptr, goff, out_hmeans + (size_t)(l-1)*GG*DD, NN);
        k_agg<<<AGG_GRID, 256, 0, stream>>>(xb, yb, zb, rowptr, eidx, epsA, l, pstat, pg, pb);
        k_gemm<0,0,1,0><<<GGRID, 256, 0, stream>>>(zb, WfW1 + (size_t)l*16384, nullptr,
            nullptr, nullptr, nullptr, yb, statsIn, nullptr, nullptr, NN);
        k_gemm<2,0,1,0><<<GGRID, 256, 0, stream>>>(yb, WfW2 + (size_t)l*16384, nullptr,
            statsIn, g1 + (size_t)l*DD, b1 + (size_t)l*DD, xb, statsOut, nullptr, nullptr, NN);
    }

    // ---- pooling MLP (pW1-GEMM carries layer-2 h_means pool) ----
    k_gemm<2,0,1,1><<<GP_GRID, 256, 0, stream>>>(xb, WfPW1, nullptr,
        SR + 5*256, bng + 2*DD, bnb + 2*DD,
        yb, SR + 6*256, goff, out_hmeans + (size_t)2*GG*DD, NN);
    k_gemm<2,0,1,0><<<GGRID, 256, 0, stream>>>(yb, WfPW2, nullptr,
        SR + 6*256, pg1, pb1, zb, SR + 7*256, nullptr, nullptr, NN);
    // h_graph pool + predict (fused)
    k_poolpred<<<GG, 256, 0, stream>>>(zb, SR + 7*256, pbng, pbnb, goff,
        prW1, prb1, prW2, prb2, out_hgraph, out_pred);
}